// Round 15
// baseline (20887.495 us; speedup 1.0000x reference)
//
#include <hip/hip_runtime.h>

// ---------------- problem constants (match reference) ----------------
#define Zl      384
#define MBr     46
#define NBc     68
#define DEG     7
#define K_INFO  8448
#define N_TX    25344
#define N_LDPC  (NBc * Zl)        // 26112
#define M_CHK   (MBr * Zl)        // 17664
#define E_EDGE  (MBr * DEG * Zl)  // 123648
#define BATCH   128
#define NUM_ITER 20
#define LLR_MAXF 20.0f
#define BCAP    32

#define NTHR    256
#define GROUPS  16
#define NBLK_MAX 1024

// NUMERICS CONTRACT (validated rounds 7-13, absmax 0.0625 vs 0.45):
//  - pure f32; VN sum starts at lch[v], then messages in ASCENDING
//    edge-id order. DO NOT REORDER (other orders: 1.4-2.0 absmax).
//  - CN: two-min strict < (first-argmin), sign via parity mask.
//  - state compression EXACT (messages are +-min1/+-min2).
// Batch quads independent -> per-quad passes / slicing are order-safe.
//
// PERF MODEL (R8-R13): ~17-19us FIXED cost per dispatch (multi-XCD L2
// writeback+invalidate at kernel boundaries) dominates: R11 = 40
// dispatches x ~22us. FIX: one persistent cooperative kernel (16 groups,
// group=bid%16 -> XCD g%8, group-local sense barriers, 2 quad passes).
// R14 LESSON: 1024-block cooperative launch EXCEEDED co-residency ->
// hipErrorCooperativeLaunchTooLarge, silently no-op. Now: occupancy
// QUERY sizes the grid; if coop launch still fails, deterministic
// fallback to the proven R11 40-dispatch path.

// meta bits: [2:0]=amin, [9:3]=nm (neg mask), [10]=stot (parity)

typedef float  f4v __attribute__((ext_vector_type(4)));
typedef unsigned short u4v __attribute__((ext_vector_type(4)));

// ---------------------------------------------------------------------
// prep: lch[(2Z+n)*128 + b] = -clip(llr[b*N_TX + n])   (tiled transpose)
// ---------------------------------------------------------------------
__global__ void prep_kernel(const float* __restrict__ llr, float* __restrict__ lch) {
    __shared__ float tile[32][33];
    const int n0 = blockIdx.x * 32, b0 = blockIdx.y * 32;
    const int tx = threadIdx.x, ty = threadIdx.y;
#pragma unroll
    for (int j = 0; j < 4; ++j) {
        float v = llr[(b0 + ty + 8 * j) * N_TX + n0 + tx];
        v = fminf(fmaxf(v, -LLR_MAXF), LLR_MAXF);
        tile[ty + 8 * j][tx] = -v;          // [b_local][n_local]
    }
    __syncthreads();
#pragma unroll
    for (int j = 0; j < 4; ++j) {
        lch[(2 * Zl + n0 + ty + 8 * j) * BATCH + b0 + tx] = tile[tx][ty + 8 * j];
    }
}

// ---------------------------------------------------------------------
// adjacency build (deterministic ascending base-edge order) + bar init.
// badj[c*BCAP + slot] = sh | (d<<10) | (r<<13)
// ---------------------------------------------------------------------
__global__ void base_build_kernel(const int* __restrict__ col,
                                  int* __restrict__ bcount, int* __restrict__ badj,
                                  unsigned* __restrict__ bar) {
    __shared__ int sc[MBr * DEG];
    __shared__ int ssh[MBr * DEG];
    const int t = threadIdx.x;
    if (t < MBr * DEG) {
        const int v0 = col[t * Zl];         // col[be*Z] = c*Z + shift
        const int c  = v0 / Zl;
        sc[t]  = c;
        ssh[t] = v0 - c * Zl;
    }
    if (t < NBc) bcount[t] = 0;
    if (t < 2 * GROUPS * 16) bar[t] = 0u;   // bar_cnt + bar_gen (padded x16)
    __syncthreads();
    if (t < MBr * DEG) {
        const int c = sc[t];
        int slot = 0;
        for (int u = 0; u < t; ++u) slot += (sc[u] == c) ? 1 : 0;
        const int r = t / DEG, d = t - r * DEG;
        if (slot < BCAP) badj[c * BCAP + slot] = ssh[t] | (d << 10) | (r << 13);
        atomicAdd(&bcount[c], 1);           // order-independent (count only)
    }
}

// ---------------------------------------------------------------------
// group-local sense barrier (device-scope; safe on any placement).
// ---------------------------------------------------------------------
__device__ __forceinline__ void group_barrier(unsigned* cnt, unsigned* gen,
                                              unsigned& my_gen, int bpg) {
    __syncthreads();
    if (threadIdx.x == 0) {
        __threadfence();
        const unsigned arrived =
            __hip_atomic_fetch_add(cnt, 1u, __ATOMIC_ACQ_REL, __HIP_MEMORY_SCOPE_AGENT);
        if (arrived == (unsigned)(bpg - 1)) {
            __hip_atomic_store(cnt, 0u, __ATOMIC_RELAXED, __HIP_MEMORY_SCOPE_AGENT);
            __hip_atomic_fetch_add(gen, 1u, __ATOMIC_RELEASE, __HIP_MEMORY_SCOPE_AGENT);
        } else {
            while (__hip_atomic_load(gen, __ATOMIC_ACQUIRE, __HIP_MEMORY_SCOPE_AGENT)
                   == my_gen) {
                __builtin_amdgcn_s_sleep(8);
            }
        }
        __threadfence();
    }
    ++my_gen;
    __syncthreads();
}

// ---------------------------------------------------------------------
// persistent iteration kernel: 20 iterations x 2 quad passes per group.
// Per-element arithmetic identical to R11 (bit-exact).
// ---------------------------------------------------------------------
__global__ __launch_bounds__(NTHR, 4) void iter_kernel(
    const float* __restrict__ lch, float* __restrict__ x,
    float* __restrict__ state_f2, unsigned short* __restrict__ meta,
    const int* __restrict__ col, const int* __restrict__ bcount,
    const int* __restrict__ badj, unsigned* __restrict__ bar, int bpg)
{
    const int g  = blockIdx.x & (GROUPS - 1);   // group -> XCD g%8
    const int lb = blockIdx.x / GROUPS;         // block within group (0..bpg-1)
    const int lt = lb * NTHR + threadIdx.x;     // thread within group
    const int gthr = bpg * NTHR;
    unsigned* bar_cnt = bar + g * 16;
    unsigned* bar_gen = bar + (GROUPS + g) * 16;
    unsigned my_gen = 0;

    for (int pass = 0; pass < 2; ++pass) {
        const int q = g + GROUPS * pass;        // quad 0..31 (4 batch elems)

        for (int it = 0; it < NUM_ITER; ++it) {
            const bool first = (it == 0);
            const float* __restrict__ xs = first ? lch : x;

            // ---------------- CN phase ----------------
            for (int cn = lt; cn < M_CHK; cn += gthr) {
                const int r = cn / Zl;
                const int i = cn - r * Zl;
                const int ebase = r * DEG * Zl + i;

                float omin1[4], omin2[4];
                int oamin[4]; unsigned onm[4], ostot[4];
                if (!first) {
                    const f4v sA = ((const f4v*)state_f2)[cn * 64 + 2 * q];
                    const f4v sB = ((const f4v*)state_f2)[cn * 64 + 2 * q + 1];
                    omin1[0] = sA[0]; omin2[0] = sA[1]; omin1[1] = sA[2]; omin2[1] = sA[3];
                    omin1[2] = sB[0]; omin2[2] = sB[1]; omin1[3] = sB[2]; omin2[3] = sB[3];
                    const u4v mt = ((const u4v*)meta)[cn * 32 + q];
                    const unsigned m4[4] = {mt[0], mt[1], mt[2], mt[3]};
#pragma unroll
                    for (int c = 0; c < 4; ++c) {
                        oamin[c] = m4[c] & 7u;
                        onm[c]   = (m4[c] >> 3) & 0x7Fu;
                        ostot[c] = (m4[c] >> 10) & 1u;
                    }
                }

                float min1[4] = {1e30f, 1e30f, 1e30f, 1e30f};
                float min2[4] = {1e30f, 1e30f, 1e30f, 1e30f};
                int   amin[4] = {0, 0, 0, 0};
                unsigned nm[4] = {0u, 0u, 0u, 0u};

#pragma unroll
                for (int d = 0; d < DEG; ++d) {
                    const int e = ebase + d * Zl;
                    const int v = col[e];
                    const f4v xv = ((const f4v*)xs)[v * 32 + q];
                    float t[4] = {xv[0], xv[1], xv[2], xv[3]};
                    if (!first) {
#pragma unroll
                        for (int c = 0; c < 4; ++c) {
                            const float omag = (d == oamin[c]) ? omin2[c] : omin1[c];
                            const float mold =
                                (ostot[c] ^ ((onm[c] >> d) & 1u)) ? -omag : omag;
                            t[c] -= mold;
                        }
                    }
#pragma unroll
                    for (int c = 0; c < 4; ++c) {
                        const float mag = fabsf(t[c]);
                        nm[c] |= (t[c] < 0.f ? 1u : 0u) << d;
                        if (mag < min1[c]) { min2[c] = min1[c]; min1[c] = mag; amin[c] = d; }
                        else if (mag < min2[c]) { min2[c] = mag; }
                    }
                }

                f4v oA, oB;
                oA[0] = min1[0]; oA[1] = min2[0]; oA[2] = min1[1]; oA[3] = min2[1];
                oB[0] = min1[2]; oB[1] = min2[2]; oB[2] = min1[3]; oB[3] = min2[3];
                ((f4v*)state_f2)[cn * 64 + 2 * q]     = oA;
                ((f4v*)state_f2)[cn * 64 + 2 * q + 1] = oB;
                u4v mo;
#pragma unroll
                for (int c = 0; c < 4; ++c) {
                    const unsigned mv = (unsigned)amin[c] | (nm[c] << 3) |
                                        ((unsigned)(__popc(nm[c]) & 1) << 10);
                    mo[c] = (unsigned short)mv;
                }
                ((u4v*)meta)[cn * 32 + q] = mo;
            }

            group_barrier(bar_cnt, bar_gen, my_gen, bpg);

            // ------------- VN phase (LCH-FIRST, ascending edges) -------------
            for (int v = lt; v < N_LDPC; v += gthr) {
                const int c = v / Zl;
                const int j = v - c * Zl;
                const int cntc = min(bcount[c], BCAP);
                const int* bp = badj + c * BCAP;
                const f4v l4 = ((const f4v*)lch)[v * 32 + q];
                float s0 = l4[0], s1 = l4[1], s2 = l4[2], s3 = l4[3];  // lch FIRST
                for (int k = 0; k < cntc; ++k) {
                    const int pk = bp[k];
                    const int sh = pk & 0x3FF;
                    const int d  = (pk >> 10) & 7;
                    const int r  = pk >> 13;
                    int i = j - sh;
                    if (i < 0) i += Zl;
                    const int cn = r * Zl + i;
                    const f4v sA = ((const f4v*)state_f2)[cn * 64 + 2 * q];
                    const f4v sB = ((const f4v*)state_f2)[cn * 64 + 2 * q + 1];
                    const u4v mt = ((const u4v*)meta)[cn * 32 + q];
                    const unsigned m4[4] = {mt[0], mt[1], mt[2], mt[3]};
                    const float mn1[4] = {sA[0], sA[2], sB[0], sB[2]};
                    const float mn2[4] = {sA[1], sA[3], sB[1], sB[3]};
                    float val[4];
#pragma unroll
                    for (int cc = 0; cc < 4; ++cc) {
                        const int am = m4[cc] & 7u;
                        const unsigned nmv = (m4[cc] >> 3) & 0x7Fu;
                        const unsigned st  = (m4[cc] >> 10) & 1u;
                        const float mag = (d == am) ? mn2[cc] : mn1[cc];
                        val[cc] = (st ^ ((nmv >> d) & 1u)) ? -mag : mag;
                    }
                    s0 += val[0]; s1 += val[1]; s2 += val[2]; s3 += val[3];
                }
                f4v o; o[0] = s0; o[1] = s1; o[2] = s2; o[3] = s3;
                ((f4v*)x)[v * 32 + q] = o;
            }

            group_barrier(bar_cnt, bar_gen, my_gen, bpg);
        }
    }
}

// ================= fallback path: R11 kernels (proven 911us) =================
template <bool FIRST>
__global__ void cn_kernel(const float* __restrict__ x,
                          float* __restrict__ state_f2,
                          unsigned short* __restrict__ meta,
                          const int* __restrict__ col) {
    const int qg   = blockIdx.x & 7;
    const int tile = blockIdx.x >> 3;
    const int nl   = threadIdx.x >> 2;
    const int ql   = threadIdx.x & 3;
    const int q    = qg * 4 + ql;
    const int cn   = tile * 64 + nl;
    const int r    = cn / Zl;
    const int i    = cn - r * Zl;
    const int ebase = r * DEG * Zl + i;

    float omin1[4], omin2[4];
    int oamin[4]; unsigned onm[4], ostot[4];
    if (!FIRST) {
        const f4v sA = ((const f4v*)state_f2)[cn * 64 + 2 * q];
        const f4v sB = ((const f4v*)state_f2)[cn * 64 + 2 * q + 1];
        omin1[0] = sA[0]; omin2[0] = sA[1]; omin1[1] = sA[2]; omin2[1] = sA[3];
        omin1[2] = sB[0]; omin2[2] = sB[1]; omin1[3] = sB[2]; omin2[3] = sB[3];
        const u4v mt = ((const u4v*)meta)[cn * 32 + q];
        const unsigned m4[4] = {mt[0], mt[1], mt[2], mt[3]};
#pragma unroll
        for (int c = 0; c < 4; ++c) {
            oamin[c] = m4[c] & 7u;
            onm[c]   = (m4[c] >> 3) & 0x7Fu;
            ostot[c] = (m4[c] >> 10) & 1u;
        }
    }

    float min1[4] = {1e30f, 1e30f, 1e30f, 1e30f};
    float min2[4] = {1e30f, 1e30f, 1e30f, 1e30f};
    int   amin[4] = {0, 0, 0, 0};
    unsigned nm[4] = {0u, 0u, 0u, 0u};

#pragma unroll
    for (int d = 0; d < DEG; ++d) {
        const int e = ebase + d * Zl;
        const int v = col[e];
        const f4v xv = ((const f4v*)x)[v * 32 + q];
        float t[4] = {xv[0], xv[1], xv[2], xv[3]};
        if (!FIRST) {
#pragma unroll
            for (int c = 0; c < 4; ++c) {
                const float omag = (d == oamin[c]) ? omin2[c] : omin1[c];
                const float mold = (ostot[c] ^ ((onm[c] >> d) & 1u)) ? -omag : omag;
                t[c] -= mold;
            }
        }
#pragma unroll
        for (int c = 0; c < 4; ++c) {
            const float mag = fabsf(t[c]);
            nm[c] |= (t[c] < 0.f ? 1u : 0u) << d;
            if (mag < min1[c]) { min2[c] = min1[c]; min1[c] = mag; amin[c] = d; }
            else if (mag < min2[c]) { min2[c] = mag; }
        }
    }

    f4v oA, oB;
    oA[0] = min1[0]; oA[1] = min2[0]; oA[2] = min1[1]; oA[3] = min2[1];
    oB[0] = min1[2]; oB[1] = min2[2]; oB[2] = min1[3]; oB[3] = min2[3];
    ((f4v*)state_f2)[cn * 64 + 2 * q]     = oA;
    ((f4v*)state_f2)[cn * 64 + 2 * q + 1] = oB;
    u4v mo;
#pragma unroll
    for (int c = 0; c < 4; ++c) {
        const unsigned mv = (unsigned)amin[c] | (nm[c] << 3) |
                            ((unsigned)(__popc(nm[c]) & 1) << 10);
        mo[c] = (unsigned short)mv;
    }
    ((u4v*)meta)[cn * 32 + q] = mo;
}

__global__ void vn_kernel(const float* __restrict__ lch,
                          const float* __restrict__ state_f2,
                          const unsigned short* __restrict__ meta,
                          const int* __restrict__ bcount, const int* __restrict__ badj,
                          float* __restrict__ x) {
    const int qg   = blockIdx.x & 7;
    const int tile = blockIdx.x >> 3;
    const int nl   = threadIdx.x >> 2;
    const int ql   = threadIdx.x & 3;
    const int q    = qg * 4 + ql;
    const int v    = tile * 64 + nl;
    const int c    = v / Zl;
    const int j    = v - c * Zl;
    const int cnt  = min(bcount[c], BCAP);
    const int* bp  = badj + c * BCAP;
    const f4v l4 = ((const f4v*)lch)[v * 32 + q];
    float s0 = l4[0], s1 = l4[1], s2 = l4[2], s3 = l4[3];
    for (int k = 0; k < cnt; ++k) {
        const int pk = bp[k];
        const int sh = pk & 0x3FF;
        const int d  = (pk >> 10) & 7;
        const int r  = pk >> 13;
        int i = j - sh;
        if (i < 0) i += Zl;
        const int cn = r * Zl + i;
        const f4v sA = ((const f4v*)state_f2)[cn * 64 + 2 * q];
        const f4v sB = ((const f4v*)state_f2)[cn * 64 + 2 * q + 1];
        const u4v mt = ((const u4v*)meta)[cn * 32 + q];
        const unsigned m4[4] = {mt[0], mt[1], mt[2], mt[3]};
        const float mn1[4] = {sA[0], sA[2], sB[0], sB[2]};
        const float mn2[4] = {sA[1], sA[3], sB[1], sB[3]};
        float val[4];
#pragma unroll
        for (int cc = 0; cc < 4; ++cc) {
            const int am = m4[cc] & 7u;
            const unsigned nmv = (m4[cc] >> 3) & 0x7Fu;
            const unsigned st  = (m4[cc] >> 10) & 1u;
            const float mag = (d == am) ? mn2[cc] : mn1[cc];
            val[cc] = (st ^ ((nmv >> d) & 1u)) ? -mag : mag;
        }
        s0 += val[0]; s1 += val[1]; s2 += val[2]; s3 += val[3];
    }
    f4v o; o[0] = s0; o[1] = s1; o[2] = s2; o[3] = s3;
    ((f4v*)x)[v * 32 + q] = o;
}

// ---------------------------------------------------------------------
// output: out[b*K + k] = -x[k*128 + b], k < K_INFO   (tiled transpose)
// ---------------------------------------------------------------------
__global__ void out_kernel(const float* __restrict__ x, float* __restrict__ out) {
    __shared__ float tile[32][33];
    const int k0 = blockIdx.x * 32, b0 = blockIdx.y * 32;
    const int tx = threadIdx.x, ty = threadIdx.y;
#pragma unroll
    for (int j = 0; j < 4; ++j) {
        tile[ty + 8 * j][tx] = -x[(k0 + ty + 8 * j) * BATCH + b0 + tx];
    }
    __syncthreads();
#pragma unroll
    for (int j = 0; j < 4; ++j) {
        out[(b0 + ty + 8 * j) * K_INFO + k0 + tx] = tile[tx][ty + 8 * j];
    }
}

// ---------------------------------------------------------------------
extern "C" void kernel_launch(void* const* d_in, const int* in_sizes, int n_in,
                              void* d_out, int out_size, void* d_ws, size_t ws_size,
                              hipStream_t stream) {
    const float* llr = (const float*)d_in[0];
    // d_in[1] = row (unused: row index derivable from edge-id structure)
    const int* col = (const int*)d_in[2];
    float* out = (float*)d_out;

    char* ws = (char*)d_ws;
    float* lch   = (float*)ws;                                   // 13,369,344 B
    float* x     = lch + (size_t)N_LDPC * BATCH;                 // 13,369,344 B
    float* state = x + (size_t)N_LDPC * BATCH;                   // 18,087,936 B
    unsigned short* meta = (unsigned short*)(state + (size_t)M_CHK * BATCH * 2); // 4,521,984 B
    int* bcount = (int*)(meta + (size_t)M_CHK * BATCH);          // 68*4
    int* badj   = bcount + NBc;                                  // 68*32*4
    unsigned* bar = (unsigned*)(badj + NBc * BCAP);              // 2*16*16*4 B

    hipMemsetAsync(lch, 0, (size_t)(2 * Zl) * BATCH * sizeof(float), stream);
    prep_kernel<<<dim3(N_TX / 32, BATCH / 32), dim3(32, 8), 0, stream>>>(llr, lch);

    base_build_kernel<<<1, 512, 0, stream>>>(col, bcount, badj, bar);

    // size the cooperative grid from measured occupancy (deterministic)
    int maxb = 0;
    (void)hipOccupancyMaxActiveBlocksPerMultiprocessor(&maxb, iter_kernel, NTHR, 0);
    if (maxb < 1) maxb = 1;
    int nblk = maxb * 256;
    if (nblk > NBLK_MAX) nblk = NBLK_MAX;
    nblk = (nblk / GROUPS) * GROUPS;         // multiple of 16 groups
    if (nblk < GROUPS) nblk = GROUPS;
    int bpg = nblk / GROUPS;

    void* args[] = {(void*)&lch, (void*)&x, (void*)&state, (void*)&meta,
                    (void*)&col, (void*)&bcount, (void*)&badj, (void*)&bar,
                    (void*)&bpg};
    hipError_t cerr = hipLaunchCooperativeKernel((void*)iter_kernel, dim3(nblk),
                                                 dim3(NTHR), args, 0, stream);

    if (cerr != hipSuccess) {
        // deterministic fallback: proven R11 multi-dispatch path
        const int cn_grid = (M_CHK / 64) * 8;    // 2208
        const int vn_grid = (N_LDPC / 64) * 8;   // 3264
        cn_kernel<true><<<cn_grid, 256, 0, stream>>>(lch, state, meta, col);
        vn_kernel<<<vn_grid, 256, 0, stream>>>(lch, state, meta, bcount, badj, x);
        for (int t = 1; t < NUM_ITER; ++t) {
            cn_kernel<false><<<cn_grid, 256, 0, stream>>>(x, state, meta, col);
            vn_kernel<<<vn_grid, 256, 0, stream>>>(lch, state, meta, bcount, badj, x);
        }
    }

    out_kernel<<<dim3(K_INFO / 32, BATCH / 32), dim3(32, 8), 0, stream>>>(x, out);
}

// Round 16
// 11079.269 us; speedup vs baseline: 1.8853x; 1.8853x over previous
//
#include <hip/hip_runtime.h>

// ---------------- problem constants (match reference) ----------------
#define Zl      384
#define MBr     46
#define NBc     68
#define DEG     7
#define K_INFO  8448
#define N_TX    25344
#define N_LDPC  (NBc * Zl)        // 26112
#define M_CHK   (MBr * Zl)        // 17664
#define E_EDGE  (MBr * DEG * Zl)  // 123648
#define BATCH   128
#define NUM_ITER 20
#define LLR_MAXF 20.0f
#define BCAP    32

#define NTHR     256
#define GROUPS   8                 // one per XCD (bid%8 round-robin)
#define SLICES   16                // 2 passes x 8 groups; 8 batch elems/slice
#define NBLK_MAX 1024

// NUMERICS CONTRACT (validated R7-R15, absmax 0.0625 vs 0.45):
//  - pure f32; VN sum starts at lch[v], then messages in ASCENDING
//    edge-id order. DO NOT REORDER (other orders: 1.4-2.0 absmax).
//  - CN: two-min strict < (first-argmin), sign via parity mask.
//  - state compression EXACT (messages are +-min1/+-min2).
// Batch elems independent -> slicing/passes order-safe (DAG unchanged).
//
// PERF MODEL (R13/R15 ERRATA): the ~910us plateau is L2/L3-throughput-
// bound; "fixed dispatch cost" was WRONG. R13/R15 regressions were
// COALESCING breaks: batch-innermost layout + batch-slicing = 32B used
// per 128B line (R15: FETCH 8.6GB = 4x overfetch, 20.9ms). FIX: SLICE-
// MAJOR layout [slice][node][8 elems] -> slice data contiguous (state
// 64B/cn, x 32B/v) = full-line coalescing AND compact per-group working
// set (~3.1MB < 4MB XCD L2). Persistent coop kernel (R15-validated
// structure): 8 groups, 2 passes x 2-quad slices, group-local barriers.

// meta bits: [2:0]=amin, [9:3]=nm (neg mask), [10]=stot (parity)

typedef float  f4v __attribute__((ext_vector_type(4)));
typedef unsigned short u4v __attribute__((ext_vector_type(4)));

// ---------------------------------------------------------------------
// per-(slice,node,half) CN update. Lane handles elems 4h..4h+3 of slice.
// Layout: states f4v idx ((s*M_CHK+cn)*4 + 2h + {0,1}); metas u4v idx
// ((s*M_CHK+cn)*2 + h); x/lch f4v idx ((s*N_LDPC+v)*2 + h).
// ---------------------------------------------------------------------
__device__ __forceinline__ void cn_node(int s, int cn, int h, bool first,
                                        const float* __restrict__ lchs,
                                        const float* __restrict__ xs,
                                        float* __restrict__ states,
                                        unsigned short* __restrict__ metas,
                                        const int* __restrict__ col) {
    const int r = cn / Zl;
    const int i = cn - r * Zl;
    const int ebase = r * DEG * Zl + i;
    const f4v* xb = (const f4v*)(first ? lchs : xs) + (size_t)s * N_LDPC * 2;
    f4v* st = (f4v*)states + ((size_t)s * M_CHK + cn) * 4 + 2 * h;
    u4v* mtp = (u4v*)metas + ((size_t)s * M_CHK + cn) * 2 + h;

    float omin1[4], omin2[4];
    int oamin[4]; unsigned onm[4], ostot[4];
    if (!first) {
        const f4v sA = st[0];
        const f4v sB = st[1];
        omin1[0] = sA[0]; omin2[0] = sA[1]; omin1[1] = sA[2]; omin2[1] = sA[3];
        omin1[2] = sB[0]; omin2[2] = sB[1]; omin1[3] = sB[2]; omin2[3] = sB[3];
        const u4v mt = *mtp;
        const unsigned m4[4] = {mt[0], mt[1], mt[2], mt[3]};
#pragma unroll
        for (int c = 0; c < 4; ++c) {
            oamin[c] = m4[c] & 7u;
            onm[c]   = (m4[c] >> 3) & 0x7Fu;
            ostot[c] = (m4[c] >> 10) & 1u;
        }
    }

    float min1[4] = {1e30f, 1e30f, 1e30f, 1e30f};
    float min2[4] = {1e30f, 1e30f, 1e30f, 1e30f};
    int   amin[4] = {0, 0, 0, 0};
    unsigned nm[4] = {0u, 0u, 0u, 0u};

#pragma unroll
    for (int d = 0; d < DEG; ++d) {
        const int v = col[ebase + d * Zl];
        const f4v xv = xb[v * 2 + h];
        float t[4] = {xv[0], xv[1], xv[2], xv[3]};
        if (!first) {
#pragma unroll
            for (int c = 0; c < 4; ++c) {
                const float omag = (d == oamin[c]) ? omin2[c] : omin1[c];
                const float mold = (ostot[c] ^ ((onm[c] >> d) & 1u)) ? -omag : omag;
                t[c] -= mold;
            }
        }
#pragma unroll
        for (int c = 0; c < 4; ++c) {
            const float mag = fabsf(t[c]);
            nm[c] |= (t[c] < 0.f ? 1u : 0u) << d;
            if (mag < min1[c]) { min2[c] = min1[c]; min1[c] = mag; amin[c] = d; }
            else if (mag < min2[c]) { min2[c] = mag; }
        }
    }

    f4v oA, oB;
    oA[0] = min1[0]; oA[1] = min2[0]; oA[2] = min1[1]; oA[3] = min2[1];
    oB[0] = min1[2]; oB[1] = min2[2]; oB[2] = min1[3]; oB[3] = min2[3];
    st[0] = oA;
    st[1] = oB;
    u4v mo;
#pragma unroll
    for (int c = 0; c < 4; ++c) {
        const unsigned mv = (unsigned)amin[c] | (nm[c] << 3) |
                            ((unsigned)(__popc(nm[c]) & 1) << 10);
        mo[c] = (unsigned short)mv;
    }
    *mtp = mo;
}

// ---------------------------------------------------------------------
// per-(slice,vnode,half) VN update. LCH-FIRST, ascending base-edge id.
// ---------------------------------------------------------------------
__device__ __forceinline__ void vn_node(int s, int v, int h,
                                        const float* __restrict__ lchs,
                                        const float* __restrict__ states,
                                        const unsigned short* __restrict__ metas,
                                        const int* __restrict__ bcount,
                                        const int* __restrict__ badj,
                                        float* __restrict__ xs) {
    const int c = v / Zl;
    const int j = v - c * Zl;
    const int cnt = min(bcount[c], BCAP);
    const int* bp = badj + c * BCAP;
    const f4v l4 = ((const f4v*)lchs)[((size_t)s * N_LDPC + v) * 2 + h];
    float s0 = l4[0], s1 = l4[1], s2 = l4[2], s3 = l4[3];   // lch FIRST
    for (int k = 0; k < cnt; ++k) {
        const int pk = bp[k];
        const int sh = pk & 0x3FF;
        const int d  = (pk >> 10) & 7;
        const int r  = pk >> 13;
        int i = j - sh;
        if (i < 0) i += Zl;
        const int cn = r * Zl + i;
        const f4v sA = ((const f4v*)states)[((size_t)s * M_CHK + cn) * 4 + 2 * h];
        const f4v sB = ((const f4v*)states)[((size_t)s * M_CHK + cn) * 4 + 2 * h + 1];
        const u4v mt = ((const u4v*)metas)[((size_t)s * M_CHK + cn) * 2 + h];
        const unsigned m4[4] = {mt[0], mt[1], mt[2], mt[3]};
        const float mn1[4] = {sA[0], sA[2], sB[0], sB[2]};
        const float mn2[4] = {sA[1], sA[3], sB[1], sB[3]};
        float val[4];
#pragma unroll
        for (int cc = 0; cc < 4; ++cc) {
            const int am = m4[cc] & 7u;
            const unsigned nmv = (m4[cc] >> 3) & 0x7Fu;
            const unsigned st_ = (m4[cc] >> 10) & 1u;
            const float mag = (d == am) ? mn2[cc] : mn1[cc];
            val[cc] = (st_ ^ ((nmv >> d) & 1u)) ? -mag : mag;
        }
        s0 += val[0]; s1 += val[1]; s2 += val[2]; s3 += val[3];
    }
    f4v o; o[0] = s0; o[1] = s1; o[2] = s2; o[3] = s3;
    ((f4v*)xs)[((size_t)s * N_LDPC + v) * 2 + h] = o;
}

// ---------------------------------------------------------------------
// prep: lchs[b>>3][2Z+n][b&7] = -clip(llr[b*N_TX+n])  (tiled transpose)
// ---------------------------------------------------------------------
__global__ void prep_kernel(const float* __restrict__ llr, float* __restrict__ lchs) {
    __shared__ float tile[32][33];
    const int n0 = blockIdx.x * 32, b0 = blockIdx.y * 32;
    const int tx = threadIdx.x, ty = threadIdx.y;
#pragma unroll
    for (int j = 0; j < 4; ++j) {
        float v = llr[(b0 + ty + 8 * j) * N_TX + n0 + tx];
        v = fminf(fmaxf(v, -LLR_MAXF), LLR_MAXF);
        tile[ty + 8 * j][tx] = -v;          // [b_local][n_local]
    }
    __syncthreads();
    const int b = b0 + tx;
    const int s = b >> 3, e = b & 7;
#pragma unroll
    for (int j = 0; j < 4; ++j) {
        const int n = n0 + ty + 8 * j;
        lchs[((size_t)s * N_LDPC + 2 * Zl + n) * 8 + e] = tile[tx][ty + 8 * j];
    }
}

// zero the 2Z punctured rows of every slice
__global__ void zero_head_kernel(float* __restrict__ lchs) {
    const int idx = blockIdx.x * 256 + threadIdx.x;   // < SLICES * 2Z * 8
    const int per = 2 * Zl * 8;                        // 6144
    const int s = idx / per;
    const int rem = idx - s * per;
    lchs[(size_t)s * N_LDPC * 8 + rem] = 0.f;
}

// ---------------------------------------------------------------------
// adjacency build (deterministic ascending base-edge order) + bar init.
// badj[c*BCAP + slot] = sh | (d<<10) | (r<<13)
// ---------------------------------------------------------------------
__global__ void base_build_kernel(const int* __restrict__ col,
                                  int* __restrict__ bcount, int* __restrict__ badj,
                                  unsigned* __restrict__ bar) {
    __shared__ int sc[MBr * DEG];
    __shared__ int ssh[MBr * DEG];
    const int t = threadIdx.x;
    if (t < MBr * DEG) {
        const int v0 = col[t * Zl];         // col[be*Z] = c*Z + shift
        const int c  = v0 / Zl;
        sc[t]  = c;
        ssh[t] = v0 - c * Zl;
    }
    if (t < NBc) bcount[t] = 0;
    if (t < 2 * GROUPS * 16) bar[t] = 0u;   // bar_cnt + bar_gen (padded x16)
    __syncthreads();
    if (t < MBr * DEG) {
        const int c = sc[t];
        int slot = 0;
        for (int u = 0; u < t; ++u) slot += (sc[u] == c) ? 1 : 0;
        const int r = t / DEG, d = t - r * DEG;
        if (slot < BCAP) badj[c * BCAP + slot] = ssh[t] | (d << 10) | (r << 13);
        atomicAdd(&bcount[c], 1);           // order-independent (count only)
    }
}

// ---------------------------------------------------------------------
// group-local sense barrier (device-scope; safe on any placement).
// ---------------------------------------------------------------------
__device__ __forceinline__ void group_barrier(unsigned* cnt, unsigned* gen,
                                              unsigned& my_gen, int bpg) {
    __syncthreads();
    if (threadIdx.x == 0) {
        __threadfence();
        const unsigned arrived =
            __hip_atomic_fetch_add(cnt, 1u, __ATOMIC_ACQ_REL, __HIP_MEMORY_SCOPE_AGENT);
        if (arrived == (unsigned)(bpg - 1)) {
            __hip_atomic_store(cnt, 0u, __ATOMIC_RELAXED, __HIP_MEMORY_SCOPE_AGENT);
            __hip_atomic_fetch_add(gen, 1u, __ATOMIC_RELEASE, __HIP_MEMORY_SCOPE_AGENT);
        } else {
            while (__hip_atomic_load(gen, __ATOMIC_ACQUIRE, __HIP_MEMORY_SCOPE_AGENT)
                   == my_gen) {
                __builtin_amdgcn_s_sleep(8);
            }
        }
        __threadfence();
    }
    ++my_gen;
    __syncthreads();
}

// ---------------------------------------------------------------------
// persistent kernel: 8 groups; each runs 20 iters for slice g*2, then
// slice g*2+1. Group-local barriers; slices are disjoint across groups.
// ---------------------------------------------------------------------
__global__ __launch_bounds__(NTHR) void iter_kernel(
    const float* __restrict__ lchs, float* __restrict__ xs,
    float* __restrict__ states, unsigned short* __restrict__ metas,
    const int* __restrict__ col, const int* __restrict__ bcount,
    const int* __restrict__ badj, unsigned* __restrict__ bar, int bpg)
{
    const int g  = blockIdx.x & (GROUPS - 1);
    const int lb = blockIdx.x >> 3;
    const int lt = lb * NTHR + threadIdx.x;
    const int gthr = bpg * NTHR;
    unsigned* bar_cnt = bar + g * 16;
    unsigned* bar_gen = bar + (GROUPS + g) * 16;
    unsigned my_gen = 0;

    for (int pass = 0; pass < 2; ++pass) {
        const int s = g * 2 + pass;

        for (int it = 0; it < NUM_ITER; ++it) {
            const bool first = (it == 0);

            for (int idx = lt; idx < M_CHK * 2; idx += gthr) {
                cn_node(s, idx >> 1, idx & 1, first, lchs, xs, states, metas, col);
            }
            group_barrier(bar_cnt, bar_gen, my_gen, bpg);

            for (int idx = lt; idx < N_LDPC * 2; idx += gthr) {
                vn_node(s, idx >> 1, idx & 1, lchs, states, metas, bcount, badj, xs);
            }
            group_barrier(bar_cnt, bar_gen, my_gen, bpg);
        }
    }
}

// ============== fallback: 40-dispatch path (slice-major port) ==============
template <bool FIRST>
__global__ void cn_fb(const float* __restrict__ lchs, const float* __restrict__ xs,
                      float* __restrict__ states, unsigned short* __restrict__ metas,
                      const int* __restrict__ col) {
    const int s = blockIdx.y;
    const int idx = blockIdx.x * NTHR + threadIdx.x;   // < M_CHK*2
    cn_node(s, idx >> 1, idx & 1, FIRST, lchs, xs, states, metas, col);
}

__global__ void vn_fb(const float* __restrict__ lchs, const float* __restrict__ states,
                      const unsigned short* __restrict__ metas,
                      const int* __restrict__ bcount, const int* __restrict__ badj,
                      float* __restrict__ xs) {
    const int s = blockIdx.y;
    const int idx = blockIdx.x * NTHR + threadIdx.x;   // < N_LDPC*2
    vn_node(s, idx >> 1, idx & 1, lchs, states, metas, bcount, badj, xs);
}

// ---------------------------------------------------------------------
// output: out[b*K + k] = -xs[(b>>3)][k][b&7]   (tiled transpose)
// ---------------------------------------------------------------------
__global__ void out_kernel(const float* __restrict__ xs, float* __restrict__ out) {
    __shared__ float tile[32][33];
    const int k0 = blockIdx.x * 32, b0 = blockIdx.y * 32;
    const int tx = threadIdx.x, ty = threadIdx.y;
    const int b = b0 + tx;
    const int s = b >> 3, e = b & 7;
#pragma unroll
    for (int j = 0; j < 4; ++j) {
        const int k = k0 + ty + 8 * j;
        tile[ty + 8 * j][tx] = -xs[((size_t)s * N_LDPC + k) * 8 + e];
    }
    __syncthreads();
#pragma unroll
    for (int j = 0; j < 4; ++j) {
        out[(b0 + ty + 8 * j) * K_INFO + k0 + tx] = tile[tx][ty + 8 * j];
    }
}

// ---------------------------------------------------------------------
extern "C" void kernel_launch(void* const* d_in, const int* in_sizes, int n_in,
                              void* d_out, int out_size, void* d_ws, size_t ws_size,
                              hipStream_t stream) {
    const float* llr = (const float*)d_in[0];
    // d_in[1] = row (unused: row index derivable from edge-id structure)
    const int* col = (const int*)d_in[2];
    float* out = (float*)d_out;

    char* ws = (char*)d_ws;
    float* lchs  = (float*)ws;                                   // 13,369,344 B
    float* xs    = lchs + (size_t)SLICES * N_LDPC * 8;           // 13,369,344 B
    float* states = xs + (size_t)SLICES * N_LDPC * 8;            // 18,087,936 B
    unsigned short* metas =
        (unsigned short*)(states + (size_t)SLICES * M_CHK * 16); // 4,521,984 B
    int* bcount = (int*)(metas + (size_t)SLICES * M_CHK * 8);    // 68*4
    int* badj   = bcount + NBc;                                  // 68*32*4
    unsigned* bar = (unsigned*)(badj + NBc * BCAP);              // 256*4 B

    zero_head_kernel<<<(SLICES * 2 * Zl * 8) / 256, 256, 0, stream>>>(lchs);
    prep_kernel<<<dim3(N_TX / 32, BATCH / 32), dim3(32, 8), 0, stream>>>(llr, lchs);
    base_build_kernel<<<1, 512, 0, stream>>>(col, bcount, badj, bar);

    // size the cooperative grid from occupancy (deterministic each call)
    int maxb = 0;
    (void)hipOccupancyMaxActiveBlocksPerMultiprocessor(&maxb, iter_kernel, NTHR, 0);
    if (maxb < 1) maxb = 1;
    int nblk = maxb * 256;                   // 256 CUs
    if (nblk > NBLK_MAX) nblk = NBLK_MAX;
    nblk = (nblk / GROUPS) * GROUPS;
    if (nblk < GROUPS) nblk = GROUPS;
    int bpg = nblk / GROUPS;

    void* args[] = {(void*)&lchs, (void*)&xs, (void*)&states, (void*)&metas,
                    (void*)&col, (void*)&bcount, (void*)&badj, (void*)&bar,
                    (void*)&bpg};
    hipError_t cerr = hipLaunchCooperativeKernel((void*)iter_kernel, dim3(nblk),
                                                 dim3(NTHR), args, 0, stream);

    if (cerr != hipSuccess) {
        // deterministic fallback: 40 dispatches, slice-major, full batch
        const dim3 cn_grid(M_CHK * 2 / NTHR, SLICES);    // (138,16)
        const dim3 vn_grid(N_LDPC * 2 / NTHR, SLICES);   // (204,16)
        cn_fb<true><<<cn_grid, NTHR, 0, stream>>>(lchs, xs, states, metas, col);
        vn_fb<<<vn_grid, NTHR, 0, stream>>>(lchs, states, metas, bcount, badj, xs);
        for (int t = 1; t < NUM_ITER; ++t) {
            cn_fb<false><<<cn_grid, NTHR, 0, stream>>>(lchs, xs, states, metas, col);
            vn_fb<<<vn_grid, NTHR, 0, stream>>>(lchs, states, metas, bcount, badj, xs);
        }
    }

    out_kernel<<<dim3(K_INFO / 32, BATCH / 32), dim3(32, 8), 0, stream>>>(xs, out);
}